// Round 5
// baseline (318.871 us; speedup 1.0000x reference)
//
#include <hip/hip_runtime.h>
#include <math.h>

#define NPTS 200000
#define KNBR 16
#define CDIM 32
#define NITEM (NPTS * KNBR)          // 3,200,000
#define TEMP 0.1f
#define WEIGHT 0.1f
#define EPSV 1e-8f

#define NSHARD 8
#define SHARD_ROWS 25000             // NPTS / NSHARD
#define NBINBLK 512                  // binning blocks
#define ITEMS_PER_BLK (NITEM / NBINBLK)   // 6250
#define BPS 256                      // gather blocks per shard

// ---- workspace layout (all offsets multiple of 256) ----
#define TBL_OFF      256
#define TBL_BYTES    (NPTS * CDIM)                 // 6,400,000 (fp8)
#define ACC_OFF      (TBL_OFF + TBL_BYTES)         // 6,400,256
#define ACC_BYTES    (3 * NPTS * 4)                // 2,400,000
#define HIST_OFF     (ACC_OFF + ACC_BYTES)         // 8,800,256
#define HIST_N       (NSHARD * NBINBLK)            // 4096
#define BASE_OFF     (HIST_OFF + HIST_N * 4)
#define SSTART_OFF   (BASE_OFF + HIST_N * 4)
#define ITEMS_OFF    8833280                       // aligned past SSTART
#define WS_NEEDED    ((size_t)ITEMS_OFF + (size_t)NITEM * 8)   // ~34.4 MB

typedef float v2f __attribute__((ext_vector_type(2)));

// ---------------- pre-pass: f32 features -> packed fp8 e4m3 table ----------
__global__ __launch_bounds__(256) void to_fp8(const float* __restrict__ f,
                                              unsigned* __restrict__ o) {
    const int i = blockIdx.x * 256 + threadIdx.x;   // 800000 threads exact
    const float4 a = ((const float4*)f)[2 * i];
    const float4 b = ((const float4*)f)[2 * i + 1];
    int w0 = 0, w1 = 0;
    w0 = __builtin_amdgcn_cvt_pk_fp8_f32(a.x, a.y, w0, false);
    w0 = __builtin_amdgcn_cvt_pk_fp8_f32(a.z, a.w, w0, true);
    w1 = __builtin_amdgcn_cvt_pk_fp8_f32(b.x, b.y, w1, false);
    w1 = __builtin_amdgcn_cvt_pk_fp8_f32(b.z, b.w, w1, true);
    ((uint2*)o)[i] = make_uint2((unsigned)w0, (unsigned)w1);
}

// ---------------- P1a: per-(block,shard) histogram --------------------------
__global__ __launch_bounds__(256) void bin_count(const int* __restrict__ nbr,
                                                 int* __restrict__ cnt) {
    __shared__ int h[NSHARD];
    const int tid = threadIdx.x;
    if (tid < NSHARD) h[tid] = 0;
    __syncthreads();
    const int lane = tid & 63;
    const unsigned long long mlt = (1ull << lane) - 1ull;
    const int lo = blockIdx.x * ITEMS_PER_BLK;
    const int hi = lo + ITEMS_PER_BLK;
    for (int i = lo + tid; i < hi; i += 256) {
        const unsigned idx = (unsigned)nbr[i];
        const int sh = (int)(idx / (unsigned)SHARD_ROWS);
        #pragma unroll
        for (int s = 0; s < NSHARD; ++s) {
            const bool mine = (sh == s);
            const unsigned long long m = __ballot(mine);
            if (mine && (m & mlt) == 0ull)           // leader lane
                atomicAdd(&h[s], __popcll(m));
        }
    }
    __syncthreads();
    if (tid < NSHARD) cnt[tid * NBINBLK + blockIdx.x] = h[tid];  // shard-major
}

// ---------------- P1b: exclusive scan of 4096 (single block) ---------------
__global__ __launch_bounds__(256) void scan_hist(const int* __restrict__ cnt,
                                                 int* __restrict__ base,
                                                 int* __restrict__ sstart) {
    __shared__ int lds[HIST_N];
    __shared__ int part[256];
    const int t = threadIdx.x;
    for (int i = t; i < HIST_N; i += 256) lds[i] = cnt[i];
    __syncthreads();
    int s = 0;
    #pragma unroll
    for (int j = 0; j < 16; ++j) s += lds[t * 16 + j];
    part[t] = s;
    __syncthreads();
    for (int off = 1; off < 256; off <<= 1) {
        int v = (t >= off) ? part[t - off] : 0;
        __syncthreads();
        part[t] += v;
        __syncthreads();
    }
    int run = (t == 0) ? 0 : part[t - 1];
    #pragma unroll
    for (int j = 0; j < 16; ++j) {
        const int c = lds[t * 16 + j];
        lds[t * 16 + j] = run;
        run += c;
    }
    __syncthreads();
    for (int i = t; i < HIST_N; i += 256) base[i] = lds[i];
    if (t < NSHARD) sstart[t] = lds[t * NBINBLK];
    if (t == 0) sstart[NSHARD] = NITEM;
}

// ---------------- P1c: scatter items into shard-major list -----------------
__global__ __launch_bounds__(256) void bin_scatter(const int* __restrict__ nbr,
                                                   const int* __restrict__ base,
                                                   uint2* __restrict__ items) {
    __shared__ int sbase[NSHARD];
    __shared__ int scnt[NSHARD];
    const int tid = threadIdx.x;
    if (tid < NSHARD) {
        sbase[tid] = base[tid * NBINBLK + blockIdx.x];
        scnt[tid] = 0;
    }
    __syncthreads();
    const int lane = tid & 63;
    const unsigned long long mlt = (1ull << lane) - 1ull;
    const int lo = blockIdx.x * ITEMS_PER_BLK;
    const int hi = lo + ITEMS_PER_BLK;
    for (int i = lo + tid; i < hi; i += 256) {
        const unsigned idx = (unsigned)nbr[i];
        const int p = i >> 4;
        const int sh = (int)(idx / (unsigned)SHARD_ROWS);
        #pragma unroll
        for (int s = 0; s < NSHARD; ++s) {
            const bool mine = (sh == s);
            const unsigned long long m = __ballot(mine);
            if (mine) {
                const int prior = __popcll(m & mlt);
                const int leader = __ffsll((unsigned long long)m) - 1;
                int bofs = 0;
                if (lane == leader) bofs = atomicAdd(&scnt[s], __popcll(m));
                bofs = __shfl(bofs, leader);
                items[sbase[s] + bofs + prior] = make_uint2((unsigned)p, idx);
            }
        }
    }
}

// ---------------- P2: sharded gather + unnormalized softmax accumulate -----
// grid = NSHARD*BPS; shard = blockIdx%8 -> consistent XCD via round-robin.
__global__ __launch_bounds__(256) void gather_accum(
    const unsigned char* __restrict__ tbl,
    const int* __restrict__ labels,
    const uint2* __restrict__ items,
    const int* __restrict__ sstart,
    float* __restrict__ accN, float* __restrict__ accP,
    float* __restrict__ accC) {
    const int s = blockIdx.x & (NSHARD - 1);
    const int t = blockIdx.x >> 3;
    const int i0 = sstart[s];
    const int n = sstart[s + 1] - i0;
    const int nChunks = (n + 255) >> 8;
    for (int c = t; c < nChunks; c += BPS) {
        const int g = c * 256 + threadIdx.x;
        if (g < n) {
            const uint2 it = items[i0 + g];
            const int p = (int)it.x;
            const int idx = (int)it.y;
            const uint4 nv0 = *(const uint4*)(tbl + (size_t)idx * CDIM);
            const uint4 nv1 = *(const uint4*)(tbl + (size_t)idx * CDIM + 16);
            const uint4 cv0 = *(const uint4*)(tbl + (size_t)p * CDIM);
            const uint4 cv1 = *(const uint4*)(tbl + (size_t)p * CDIM + 16);
            const unsigned* pn0 = (const unsigned*)&nv0;
            const unsigned* pn1 = (const unsigned*)&nv1;
            const unsigned* pc0 = (const unsigned*)&cv0;
            const unsigned* pc1 = (const unsigned*)&cv1;
            float d2 = 0.f;
            #pragma unroll
            for (int q = 0; q < 4; ++q) {
                v2f nl = __builtin_amdgcn_cvt_pk_f32_fp8((int)pn0[q], false);
                v2f nh = __builtin_amdgcn_cvt_pk_f32_fp8((int)pn0[q], true);
                v2f cl = __builtin_amdgcn_cvt_pk_f32_fp8((int)pc0[q], false);
                v2f ch = __builtin_amdgcn_cvt_pk_f32_fp8((int)pc0[q], true);
                float a0 = cl.x - nl.x, a1 = cl.y - nl.y;
                float a2 = ch.x - nh.x, a3 = ch.y - nh.y;
                d2 += a0 * a0 + a1 * a1 + a2 * a2 + a3 * a3;
            }
            #pragma unroll
            for (int q = 0; q < 4; ++q) {
                v2f nl = __builtin_amdgcn_cvt_pk_f32_fp8((int)pn1[q], false);
                v2f nh = __builtin_amdgcn_cvt_pk_f32_fp8((int)pn1[q], true);
                v2f cl = __builtin_amdgcn_cvt_pk_f32_fp8((int)pc1[q], false);
                v2f ch = __builtin_amdgcn_cvt_pk_f32_fp8((int)pc1[q], true);
                float a0 = cl.x - nl.x, a1 = cl.y - nl.y;
                float a2 = ch.x - nh.x, a3 = ch.y - nh.y;
                d2 += a0 * a0 + a1 * a1 + a2 * a2 + a3 * a3;
            }
            const float dist = sqrtf(d2 + EPSV);
            const float u = expf(dist * (-1.0f / TEMP));   // unnormalized; safe (see note)
            atomicAdd(&accN[p], u);
            if (labels[idx] == labels[p]) {
                atomicAdd(&accP[p], u);
                atomicAdd(&accC[p], 1.0f);
            }
        }
    }
}

// ---------------- P3: masked loss reduction --------------------------------
__global__ __launch_bounds__(256) void reduce_loss(
    const float* __restrict__ accN, const float* __restrict__ accP,
    const float* __restrict__ accC, float* __restrict__ ws) {
    const int p = blockIdx.x * 256 + threadIdx.x;
    float l = 0.f, v = 0.f;
    if (p < NPTS) {
        const float cn = accC[p];
        if (cn > 0.5f && cn < 15.5f) {
            const float ratio = accP[p] / fmaxf(accN[p], 1e-38f);
            l = -logf(ratio + EPSV);
            v = 1.f;
        }
    }
    #pragma unroll
    for (int off = 1; off <= 32; off <<= 1) {
        l += __shfl_xor(l, off);
        v += __shfl_xor(v, off);
    }
    __shared__ float sl, sv;
    if (threadIdx.x == 0) { sl = 0.f; sv = 0.f; }
    __syncthreads();
    if ((threadIdx.x & 63) == 0) {
        atomicAdd(&sl, l);
        atomicAdd(&sv, v);
    }
    __syncthreads();
    if (threadIdx.x == 0) {
        atomicAdd(&ws[0], sl);
        atomicAdd(&ws[1], sv);
    }
}

__global__ void contrast_finalize(const float* __restrict__ ws,
                                  float* __restrict__ out) {
    const float denom = fmaxf(ws[1], 1.f);
    out[0] = ws[0] / denom * WEIGHT;
}

// ---------------- fallback: R4 direct-gather fp8 kernel --------------------
__global__ __launch_bounds__(256) void contrast_fp8(
    const unsigned char* __restrict__ tbl,
    const int* __restrict__ labels,
    const int* __restrict__ nbr,
    float* __restrict__ ws) {
    const int lane = threadIdx.x & 63;
    const int wave = threadIdx.x >> 6;
    const int p0 = blockIdx.x * 64 + wave * 16;
    const int h = lane >> 1;
    const int c = lane & 1;
    const int base = p0 * KNBR;
    int idxq[4], labnq[4];
    #pragma unroll
    for (int t = 0; t < 4; ++t) idxq[t] = nbr[base + t * 64 + lane];
    #pragma unroll
    for (int t = 0; t < 4; ++t) labnq[t] = labels[idxq[t]];
    const int labc_l = labels[p0 + (lane & 15)];
    int ridx[8];
    #pragma unroll
    for (int j = 0; j < 8; ++j)
        ridx[j] = __shfl(idxq[j >> 1], 32 * (j & 1) + h);
    uint4 v[8];
    #pragma unroll
    for (int j = 0; j < 8; ++j)
        v[j] = *(const uint4*)(tbl + (size_t)ridx[j] * CDIM + 16 * c);
    uint4 cen[8];
    #pragma unroll
    for (int j = 0; j < 8; ++j)
        cen[j] = *(const uint4*)(tbl + (size_t)(p0 + 2 * j + (h >> 4)) * CDIM + 16 * c);
    float dj[8];
    #pragma unroll
    for (int j = 0; j < 8; ++j) {
        const unsigned* pv = (const unsigned*)&v[j];
        const unsigned* pc = (const unsigned*)&cen[j];
        float d2 = 0.f;
        #pragma unroll
        for (int q = 0; q < 4; ++q) {
            v2f nl = __builtin_amdgcn_cvt_pk_f32_fp8((int)pv[q], false);
            v2f nh = __builtin_amdgcn_cvt_pk_f32_fp8((int)pv[q], true);
            v2f cl = __builtin_amdgcn_cvt_pk_f32_fp8((int)pc[q], false);
            v2f ch = __builtin_amdgcn_cvt_pk_f32_fp8((int)pc[q], true);
            float d0 = cl.x - nl.x, d1 = cl.y - nl.y;
            float d2a = ch.x - nh.x, d3 = ch.y - nh.y;
            d2 += d0 * d0 + d1 * d1 + d2a * d2a + d3 * d3;
        }
        d2 += __shfl_xor(d2, 1);
        dj[j] = sqrtf(d2 + EPSV);
    }
    float loss_acc = 0.f, valid_acc = 0.f;
    #pragma unroll
    for (int j = 0; j < 8; ++j) {
        const float d = dj[j];
        float mn = d;
        mn = fminf(mn, __shfl_xor(mn, 2));
        mn = fminf(mn, __shfl_xor(mn, 4));
        mn = fminf(mn, __shfl_xor(mn, 8));
        mn = fminf(mn, __shfl_xor(mn, 16));
        const float e = expf((mn - d) * (1.0f / TEMP));
        const int ln = __shfl(labnq[j >> 1], 32 * (j & 1) + h);
        const int lc = __shfl(labc_l, 2 * j + (h >> 4));
        const bool pos = (ln == lc);
        float pos_s = pos ? e : 0.f;
        float neg_s = e;
        float cnt_s = pos ? 1.f : 0.f;
        #pragma unroll
        for (int off = 2; off <= 16; off <<= 1) {
            pos_s += __shfl_xor(pos_s, off);
            neg_s += __shfl_xor(neg_s, off);
            cnt_s += __shfl_xor(cnt_s, off);
        }
        if (lane == 2 * j || lane == 33 + 2 * j) {
            const int icnt = (int)(cnt_s + 0.5f);
            if (icnt > 0 && icnt < KNBR) {
                loss_acc += -logf(pos_s / neg_s + EPSV);
                valid_acc += 1.f;
            }
        }
    }
    #pragma unroll
    for (int off = 1; off <= 32; off <<= 1) {
        loss_acc += __shfl_xor(loss_acc, off);
        valid_acc += __shfl_xor(valid_acc, off);
    }
    __shared__ float s_loss, s_cnt;
    if (threadIdx.x == 0) { s_loss = 0.f; s_cnt = 0.f; }
    __syncthreads();
    if (lane == 0) {
        atomicAdd(&s_loss, loss_acc);
        atomicAdd(&s_cnt, valid_acc);
    }
    __syncthreads();
    if (threadIdx.x == 0) {
        atomicAdd(&ws[0], s_loss);
        atomicAdd(&ws[1], s_cnt);
    }
}

extern "C" void kernel_launch(void* const* d_in, const int* in_sizes, int n_in,
                              void* d_out, int out_size, void* d_ws, size_t ws_size,
                              hipStream_t stream) {
    const float* features = (const float*)d_in[0];
    const int* labels     = (const int*)d_in[1];
    const int* nbr        = (const int*)d_in[2];
    float* out = (float*)d_out;
    float* ws  = (float*)d_ws;

    hipMemsetAsync(ws, 0, 8, stream);   // loss/count scalars

    if (ws_size >= WS_NEEDED) {
        unsigned char* tbl = (unsigned char*)d_ws + TBL_OFF;
        float* accN  = (float*)((char*)d_ws + ACC_OFF);
        float* accP  = accN + NPTS;
        float* accC  = accN + 2 * NPTS;
        int* cnt     = (int*)((char*)d_ws + HIST_OFF);
        int* base    = (int*)((char*)d_ws + BASE_OFF);
        int* sstart  = (int*)((char*)d_ws + SSTART_OFF);
        uint2* items = (uint2*)((char*)d_ws + ITEMS_OFF);

        hipMemsetAsync(accN, 0, ACC_BYTES, stream);
        to_fp8<<<NPTS * CDIM / 8 / 256, 256, 0, stream>>>(features, (unsigned*)tbl);
        bin_count<<<NBINBLK, 256, 0, stream>>>(nbr, cnt);
        scan_hist<<<1, 256, 0, stream>>>(cnt, base, sstart);
        bin_scatter<<<NBINBLK, 256, 0, stream>>>(nbr, base, items);
        gather_accum<<<NSHARD * BPS, 256, 0, stream>>>(tbl, labels, items, sstart,
                                                       accN, accP, accC);
        reduce_loss<<<(NPTS + 255) / 256, 256, 0, stream>>>(accN, accP, accC, ws);
    } else if (ws_size >= (size_t)(TBL_OFF + TBL_BYTES)) {
        unsigned char* tbl = (unsigned char*)d_ws + TBL_OFF;
        to_fp8<<<NPTS * CDIM / 8 / 256, 256, 0, stream>>>(features, (unsigned*)tbl);
        contrast_fp8<<<NPTS / 64, 256, 0, stream>>>(tbl, labels, nbr, ws);
    }
    contrast_finalize<<<1, 1, 0, stream>>>(ws, out);
}

// Round 6
// 278.022 us; speedup vs baseline: 1.1469x; 1.1469x over previous
//
#include <hip/hip_runtime.h>
#include <math.h>

#define NPTS 200000
#define KNBR 16
#define CDIM 32
#define NITEM (NPTS * KNBR)            // 3,200,000
#define TEMP 0.1f
#define WEIGHT 0.1f
#define EPSV 1e-8f
#define ESHIFT 70.0f                   // exp bias: cancels in pos/neg ratio

#define NSHARD 8
#define SHARD_ROWS 25000
#define NBINBLK 512
#define IPB (NITEM / NBINBLK)          // 6250 items per binning block
#define BPS 256                        // gather blocks per shard
#define CONVBLK 3125                   // to_fp8 blocks (800000 threads / 256)

// ---- workspace layout ----
#define TBL_OFF   256
#define ACC_OFF   (TBL_OFF + NPTS * CDIM)              // 6,400,256  (16 x NPTS floats)
#define CNT_OFF   (ACC_OFF + 16 * NPTS * 4)            // 19,200,256 (4096 ints)
#define BASE_OFF  (CNT_OFF + NSHARD * NBINBLK * 4)     // 19,216,640 (4097 ints)
#define ITEMS_OFF 19233280                             // aligned
#define WS_NEEDED ((size_t)ITEMS_OFF + (size_t)NITEM * 4)   // 32,033,280

typedef float v2f __attribute__((ext_vector_type(2)));

// ============ K1: fp8 conversion (blocks 0..3124) || bin count + tail scan ==
__global__ __launch_bounds__(256) void prep(const float* __restrict__ f,
                                            const int* __restrict__ nbr,
                                            unsigned* __restrict__ tbl_u,
                                            int* __restrict__ cnt,
                                            int* __restrict__ base,
                                            int* __restrict__ ctr) {
    const int tid = threadIdx.x;
    if (blockIdx.x < CONVBLK) {
        const int i = blockIdx.x * 256 + tid;
        const float4 a = ((const float4*)f)[2 * i];
        const float4 b = ((const float4*)f)[2 * i + 1];
        int w0 = 0, w1 = 0;
        w0 = __builtin_amdgcn_cvt_pk_fp8_f32(a.x, a.y, w0, false);
        w0 = __builtin_amdgcn_cvt_pk_fp8_f32(a.z, a.w, w0, true);
        w1 = __builtin_amdgcn_cvt_pk_fp8_f32(b.x, b.y, w1, false);
        w1 = __builtin_amdgcn_cvt_pk_fp8_f32(b.z, b.w, w1, true);
        ((uint2*)tbl_u)[i] = make_uint2((unsigned)w0, (unsigned)w1);
        return;
    }
    const int cb = blockIdx.x - CONVBLK;          // 0..511
    __shared__ int h[NSHARD];
    if (tid < NSHARD) h[tid] = 0;
    __syncthreads();
    const int lo = cb * IPB, hi = lo + IPB;
    for (int i = lo + tid; i < hi; i += 256) {
        const int s = (int)((unsigned)nbr[i] / (unsigned)SHARD_ROWS);
        atomicAdd(&h[s], 1);
    }
    __syncthreads();
    if (tid < NSHARD) cnt[tid * NBINBLK + cb] = h[tid];  // shard-major
    __syncthreads();
    // last count block performs the exclusive scan
    __shared__ int isLast;
    if (tid == 0) {
        __threadfence();
        isLast = (atomicAdd(ctr, 1) == NBINBLK - 1);
    }
    __syncthreads();
    if (!isLast) return;
    __shared__ int lds[NSHARD * NBINBLK];
    __shared__ int part[256];
    for (int i = tid; i < NSHARD * NBINBLK; i += 256)
        lds[i] = atomicAdd(&cnt[i], 0);           // coherent read (cross-XCD)
    __syncthreads();
    int s = 0;
    #pragma unroll
    for (int j = 0; j < 16; ++j) s += lds[tid * 16 + j];
    part[tid] = s;
    __syncthreads();
    for (int off = 1; off < 256; off <<= 1) {
        int v = (tid >= off) ? part[tid - off] : 0;
        __syncthreads();
        part[tid] += v;
        __syncthreads();
    }
    int run = (tid == 0) ? 0 : part[tid - 1];
    #pragma unroll
    for (int j = 0; j < 16; ++j) {
        const int c = lds[tid * 16 + j];
        lds[tid * 16 + j] = run;
        run += c;
    }
    __syncthreads();
    for (int i = tid; i < NSHARD * NBINBLK; i += 256) base[i] = lds[i];
    if (tid == 0) base[NSHARD * NBINBLK] = NITEM;  // sentinel
}

// ============ K2: scatter items (packed: idx_local | p_off<<15 | lab<<24) ===
__global__ __launch_bounds__(256) void scatter(const int* __restrict__ nbr,
                                               const int* __restrict__ labels,
                                               const int* __restrict__ base,
                                               unsigned* __restrict__ items) {
    const int cb = blockIdx.x;
    const int tid = threadIdx.x;
    __shared__ int sb[NSHARD], sc[NSHARD];
    if (tid < NSHARD) { sb[tid] = base[tid * NBINBLK + cb]; sc[tid] = 0; }
    __syncthreads();
    const int lo = cb * IPB, hi = lo + IPB;
    const int pbase = lo >> 4;
    for (int i = lo + tid; i < hi; i += 256) {
        const int idxv = nbr[i];
        const int s = (int)((unsigned)idxv / (unsigned)SHARD_ROWS);
        const int il = idxv - s * SHARD_ROWS;          // < 25000, 15 bits
        const int lab = labels[idxv];                  // 800KB, L2-resident
        const int poff = (i >> 4) - pbase;             // < 392, 9 bits
        const int slot = sb[s] + atomicAdd(&sc[s], 1);
        items[slot] = (unsigned)il | ((unsigned)poff << 15) | ((unsigned)lab << 24);
    }
}

// ============ K3: sharded gather, per-XCD-private accumulators ==============
// grid = NSHARD*BPS; shard = blockIdx&7 (round-robin -> consistent XCD).
// Lane pair (2k,2k+1) handles one item: 16B fp8 half-rows each.
__global__ __launch_bounds__(256) void gather(const unsigned char* __restrict__ tbl,
                                              const int* __restrict__ labels,
                                              const unsigned* __restrict__ items,
                                              const int* __restrict__ base,
                                              float* __restrict__ acc) {
    const int s = blockIdx.x & (NSHARD - 1);
    const int t = blockIdx.x >> 3;                // 0..BPS-1
    float* __restrict__ accN = acc + (size_t)s * NPTS;
    float* __restrict__ accP = acc + (size_t)(NSHARD + s) * NPTS;
    const int half = threadIdx.x & 1;
    const int pair = threadIdx.x >> 1;            // 0..127

    for (int seg = t; seg < NBINBLK; seg += BPS) {
        const int e0 = base[s * NBINBLK + seg];
        const int e1 = base[s * NBINBLK + seg + 1];   // sentinel covers the end
        const int pb = (seg * IPB) >> 4;
        for (int it0 = e0; it0 < e1; it0 += 128) {
            const int slot = it0 + pair;
            if (slot < e1) {
                const unsigned w = items[slot];
                const int il = w & 0x7fff;
                const int poff = (w >> 15) & 0x1ff;
                const int labn = (int)(w >> 24);
                const int p = pb + poff;
                const int idx = s * SHARD_ROWS + il;
                const uint4 nv = *(const uint4*)(tbl + (size_t)idx * CDIM + 16 * half);
                const uint4 cv = *(const uint4*)(tbl + (size_t)p * CDIM + 16 * half);
                const unsigned* pn = (const unsigned*)&nv;
                const unsigned* pc = (const unsigned*)&cv;
                float d2 = 0.f;
                #pragma unroll
                for (int q = 0; q < 4; ++q) {
                    v2f nl = __builtin_amdgcn_cvt_pk_f32_fp8((int)pn[q], false);
                    v2f nh = __builtin_amdgcn_cvt_pk_f32_fp8((int)pn[q], true);
                    v2f cl = __builtin_amdgcn_cvt_pk_f32_fp8((int)pc[q], false);
                    v2f ch = __builtin_amdgcn_cvt_pk_f32_fp8((int)pc[q], true);
                    float a0 = cl.x - nl.x, a1 = cl.y - nl.y;
                    float a2 = ch.x - nh.x, a3 = ch.y - nh.y;
                    d2 += a0 * a0 + a1 * a1 + a2 * a2 + a3 * a3;
                }
                d2 += __shfl_xor(d2, 1);          // combine the two 16B halves
                if (half == 0) {
                    const float dist = sqrtf(d2 + EPSV);
                    const float u = expf(ESHIFT - dist * (1.0f / TEMP));
                    atomicAdd(&accN[p], u);        // XCD-private copy: no ping-pong
                    if (labn == labels[p]) atomicAdd(&accP[p], u);
                }
            }
        }
    }
}

// ============ K4: reduce copies + recount mask + last-block finalize ========
__global__ __launch_bounds__(256) void reduce_fin(const float* __restrict__ acc,
                                                  const int* __restrict__ labels,
                                                  const int* __restrict__ nbr,
                                                  float* __restrict__ ws,
                                                  int* __restrict__ ctr,
                                                  float* __restrict__ out,
                                                  int nblocks) {
    const int tid = threadIdx.x;
    const int p = blockIdx.x * 256 + tid;
    float l = 0.f, v = 0.f;
    if (p < NPTS) {
        float N = 0.f, P = 0.f;
        #pragma unroll
        for (int c = 0; c < NSHARD; ++c) {
            N += acc[(size_t)c * NPTS + p];
            P += acc[(size_t)(NSHARD + c) * NPTS + p];
        }
        const int lc = labels[p];
        int cnt = 0;
        const int4* nb = (const int4*)(nbr + (size_t)p * KNBR);
        #pragma unroll
        for (int q = 0; q < 4; ++q) {
            const int4 i4 = nb[q];
            cnt += (labels[i4.x] == lc) + (labels[i4.y] == lc)
                 + (labels[i4.z] == lc) + (labels[i4.w] == lc);
        }
        if (cnt > 0 && cnt < KNBR) {
            l = -logf(P / N + EPSV);
            v = 1.f;
        }
    }
    #pragma unroll
    for (int off = 1; off <= 32; off <<= 1) {
        l += __shfl_xor(l, off);
        v += __shfl_xor(v, off);
    }
    __shared__ float sl, sv;
    if (tid == 0) { sl = 0.f; sv = 0.f; }
    __syncthreads();
    if ((tid & 63) == 0) { atomicAdd(&sl, l); atomicAdd(&sv, v); }
    __syncthreads();
    __shared__ int isLast;
    if (tid == 0) {
        atomicAdd(&ws[0], sl);
        atomicAdd(&ws[1], sv);
        __threadfence();
        isLast = (atomicAdd(ctr, 1) == nblocks - 1);
    }
    __syncthreads();
    if (isLast && tid == 0) {
        const float S = atomicAdd(&ws[0], 0.f);   // coherent reads
        const float C = atomicAdd(&ws[1], 0.f);
        out[0] = S / fmaxf(C, 1.f) * WEIGHT;
    }
}

// ============ fallback: R4 direct-gather fp8 (needs only 6.4MB ws) ==========
__global__ __launch_bounds__(256) void contrast_fp8(
    const unsigned char* __restrict__ tbl,
    const int* __restrict__ labels,
    const int* __restrict__ nbr,
    float* __restrict__ ws) {
    const int lane = threadIdx.x & 63;
    const int wave = threadIdx.x >> 6;
    const int p0 = blockIdx.x * 64 + wave * 16;
    const int h = lane >> 1;
    const int c = lane & 1;
    const int base = p0 * KNBR;
    int idxq[4], labnq[4];
    #pragma unroll
    for (int t = 0; t < 4; ++t) idxq[t] = nbr[base + t * 64 + lane];
    #pragma unroll
    for (int t = 0; t < 4; ++t) labnq[t] = labels[idxq[t]];
    const int labc_l = labels[p0 + (lane & 15)];
    int ridx[8];
    #pragma unroll
    for (int j = 0; j < 8; ++j)
        ridx[j] = __shfl(idxq[j >> 1], 32 * (j & 1) + h);
    uint4 v[8];
    #pragma unroll
    for (int j = 0; j < 8; ++j)
        v[j] = *(const uint4*)(tbl + (size_t)ridx[j] * CDIM + 16 * c);
    uint4 cen[8];
    #pragma unroll
    for (int j = 0; j < 8; ++j)
        cen[j] = *(const uint4*)(tbl + (size_t)(p0 + 2 * j + (h >> 4)) * CDIM + 16 * c);
    float dj[8];
    #pragma unroll
    for (int j = 0; j < 8; ++j) {
        const unsigned* pv = (const unsigned*)&v[j];
        const unsigned* pc = (const unsigned*)&cen[j];
        float d2 = 0.f;
        #pragma unroll
        for (int q = 0; q < 4; ++q) {
            v2f nl = __builtin_amdgcn_cvt_pk_f32_fp8((int)pv[q], false);
            v2f nh = __builtin_amdgcn_cvt_pk_f32_fp8((int)pv[q], true);
            v2f cl = __builtin_amdgcn_cvt_pk_f32_fp8((int)pc[q], false);
            v2f ch = __builtin_amdgcn_cvt_pk_f32_fp8((int)pc[q], true);
            float d0 = cl.x - nl.x, d1 = cl.y - nl.y;
            float d2a = ch.x - nh.x, d3 = ch.y - nh.y;
            d2 += d0 * d0 + d1 * d1 + d2a * d2a + d3 * d3;
        }
        d2 += __shfl_xor(d2, 1);
        dj[j] = sqrtf(d2 + EPSV);
    }
    float loss_acc = 0.f, valid_acc = 0.f;
    #pragma unroll
    for (int j = 0; j < 8; ++j) {
        const float d = dj[j];
        float mn = d;
        mn = fminf(mn, __shfl_xor(mn, 2));
        mn = fminf(mn, __shfl_xor(mn, 4));
        mn = fminf(mn, __shfl_xor(mn, 8));
        mn = fminf(mn, __shfl_xor(mn, 16));
        const float e = expf((mn - d) * (1.0f / TEMP));
        const int ln = __shfl(labnq[j >> 1], 32 * (j & 1) + h);
        const int lc = __shfl(labc_l, 2 * j + (h >> 4));
        const bool pos = (ln == lc);
        float pos_s = pos ? e : 0.f;
        float neg_s = e;
        float cnt_s = pos ? 1.f : 0.f;
        #pragma unroll
        for (int off = 2; off <= 16; off <<= 1) {
            pos_s += __shfl_xor(pos_s, off);
            neg_s += __shfl_xor(neg_s, off);
            cnt_s += __shfl_xor(cnt_s, off);
        }
        if (lane == 2 * j || lane == 33 + 2 * j) {
            const int icnt = (int)(cnt_s + 0.5f);
            if (icnt > 0 && icnt < KNBR) {
                loss_acc += -logf(pos_s / neg_s + EPSV);
                valid_acc += 1.f;
            }
        }
    }
    #pragma unroll
    for (int off = 1; off <= 32; off <<= 1) {
        loss_acc += __shfl_xor(loss_acc, off);
        valid_acc += __shfl_xor(valid_acc, off);
    }
    __shared__ float s_loss, s_cnt;
    if (threadIdx.x == 0) { s_loss = 0.f; s_cnt = 0.f; }
    __syncthreads();
    if (lane == 0) { atomicAdd(&s_loss, loss_acc); atomicAdd(&s_cnt, valid_acc); }
    __syncthreads();
    if (threadIdx.x == 0) { atomicAdd(&ws[0], s_loss); atomicAdd(&ws[1], s_cnt); }
}

__global__ void contrast_finalize(const float* __restrict__ ws,
                                  float* __restrict__ out) {
    out[0] = ws[0] / fmaxf(ws[1], 1.f) * WEIGHT;
}

__global__ __launch_bounds__(256) void to_fp8(const float* __restrict__ f,
                                              unsigned* __restrict__ o) {
    const int i = blockIdx.x * 256 + threadIdx.x;
    const float4 a = ((const float4*)f)[2 * i];
    const float4 b = ((const float4*)f)[2 * i + 1];
    int w0 = 0, w1 = 0;
    w0 = __builtin_amdgcn_cvt_pk_fp8_f32(a.x, a.y, w0, false);
    w0 = __builtin_amdgcn_cvt_pk_fp8_f32(a.z, a.w, w0, true);
    w1 = __builtin_amdgcn_cvt_pk_fp8_f32(b.x, b.y, w1, false);
    w1 = __builtin_amdgcn_cvt_pk_fp8_f32(b.z, b.w, w1, true);
    ((uint2*)o)[i] = make_uint2((unsigned)w0, (unsigned)w1);
}

extern "C" void kernel_launch(void* const* d_in, const int* in_sizes, int n_in,
                              void* d_out, int out_size, void* d_ws, size_t ws_size,
                              hipStream_t stream) {
    const float* features = (const float*)d_in[0];
    const int* labels     = (const int*)d_in[1];
    const int* nbr        = (const int*)d_in[2];
    float* out = (float*)d_out;
    float* ws  = (float*)d_ws;

    if (ws_size >= WS_NEEDED) {
        unsigned char* tbl = (unsigned char*)d_ws + TBL_OFF;
        float* acc   = (float*)((char*)d_ws + ACC_OFF);
        int* cnt     = (int*)((char*)d_ws + CNT_OFF);
        int* base    = (int*)((char*)d_ws + BASE_OFF);
        unsigned* it = (unsigned*)((char*)d_ws + ITEMS_OFF);
        int* ctrs    = (int*)ws + 2;   // ws[2]=scan ctr, ws[3]=finalize ctr

        hipMemsetAsync(ws, 0, 16, stream);                         // scalars+ctrs
        hipMemsetAsync(acc, 0, (size_t)16 * NPTS * 4, stream);     // 12.8 MB
        prep<<<CONVBLK + NBINBLK, 256, 0, stream>>>(features, nbr,
                                                    (unsigned*)tbl, cnt, base, ctrs);
        scatter<<<NBINBLK, 256, 0, stream>>>(nbr, labels, base, it);
        gather<<<NSHARD * BPS, 256, 0, stream>>>(tbl, labels, it, base, acc);
        const int rblocks = (NPTS + 255) / 256;   // 782
        reduce_fin<<<rblocks, 256, 0, stream>>>(acc, labels, nbr, ws,
                                                ctrs + 1, out, rblocks);
    } else {
        hipMemsetAsync(ws, 0, 16, stream);
        unsigned char* tbl = (unsigned char*)d_ws + TBL_OFF;
        to_fp8<<<CONVBLK, 256, 0, stream>>>(features, (unsigned*)tbl);
        contrast_fp8<<<NPTS / 64, 256, 0, stream>>>(tbl, labels, nbr, ws);
        contrast_finalize<<<1, 1, 0, stream>>>(ws, out);
    }
}